// Round 7
// baseline (90.795 us; speedup 1.0000x reference)
//
#include <hip/hip_runtime.h>
#include <math.h>

// Problem constants (B=8, T=1024, H=640, N_PHONE=230, N_PHONEME=96)
#define NH 640
#define NP 230
#define NM 96
#define NROWS 8192
#define MAXL 32
#define NSTEP 20            // K-steps of 32
#define NRT 512             // row-tiles of 16

// ws layout (byte offsets)
#define OFF_CNT  0
#define OFF_CSR  4096
#define OFF_B    65536      // wsB2: 20480 frag-lanes * 16 B = 327,680 B
#define OFF_A    1048576    // wsA: 655360 frag-lanes * 16 B = 10.5 MB

typedef __bf16 bf16_t;
typedef bf16_t bf16x8 __attribute__((ext_vector_type(8)));
typedef float floatx4 __attribute__((ext_vector_type(4)));

// fp32 -> bf16 round-to-nearest-even
static __device__ __forceinline__ unsigned short f2b(float f) {
    unsigned u = __float_as_uint(f);
    u += 0x7fffu + ((u >> 16) & 1u);
    return (unsigned short)(u >> 16);
}

// ---------------- Prep: CSR (blocks 0..23) + B retile (24..103) + A retile (104..2663)
__global__ __launch_bounds__(256)
void prep_kernel(const float* __restrict__ enc,
                 const float* __restrict__ f2p,
                 const float* __restrict__ mapping,
                 int* __restrict__ cnt, int* __restrict__ csr,
                 unsigned short* __restrict__ wsB2,
                 unsigned short* __restrict__ wsA) {
    const int b = blockIdx.x;
    const int tid = threadIdx.x;
    if (b < 24) {
        int wave = b * 4 + (tid >> 6);
        int lane = tid & 63;
        if (wave >= NM) return;
        int base = 0;
        #pragma unroll
        for (int c = 0; c < 4; ++c) {
            int p = c * 64 + lane;
            float v = (p < NP) ? mapping[wave * NP + p] : 0.0f;
            unsigned long long mask = __ballot(v > 0.0f);
            if (v > 0.0f) {
                int idx = base + __popcll(mask & ((1ull << lane) - 1ull));
                if (idx < MAXL) csr[wave * MAXL + idx] = p;
            }
            base += __popcll(mask);
        }
        if (lane == 0) cnt[wave] = base < MAXL ? base : MAXL;
    } else if (b < 104) {
        int g = (b - 24) * 256 + tid;          // < 20480
        int m16  = g & 15;
        int quad = (g >> 4) & 3;
        int ct   = (g >> 6) & 15;
        int s    = g >> 10;
        int n = ct * 16 + m16;
        int k0 = s * 32 + quad * 8;
        unsigned short v[8];
        #pragma unroll
        for (int j = 0; j < 8; ++j)
            v[j] = (n < NP) ? f2b(f2p[(size_t)(k0 + j) * NP + n]) : (unsigned short)0;
        *(uint4*)(wsB2 + (size_t)g * 8) = *(const uint4*)v;
    } else {
        int h = (b - 104) * 256 + tid;         // < 655360
        int m16  = h & 15;
        int quad = (h >> 4) & 3;
        int rs   = h >> 6;                     // rt*20 + s
        int s    = rs % 20;
        int rt   = rs / 20;
        const float* src = enc + (size_t)(rt * 16 + m16) * NH + s * 32 + quad * 8;
        float4 a0 = *(const float4*)(src);
        float4 a1 = *(const float4*)(src + 4);
        unsigned short v[8];
        v[0] = f2b(a0.x); v[1] = f2b(a0.y); v[2] = f2b(a0.z); v[3] = f2b(a0.w);
        v[4] = f2b(a1.x); v[5] = f2b(a1.y); v[6] = f2b(a1.z); v[7] = f2b(a1.w);
        *(uint4*)(wsA + (size_t)h * 8) = *(const uint4*)v;
    }
}

// ---------------- Main: barrier-free MFMA K-loop, all loads lane-linear.
// launch_bounds(256,4): VGPR<=128 -> 16 waves/CU (2x R3) to hide L2 latency.
__global__ __launch_bounds__(256, 4)
void fused_phonetics_kernel(const unsigned short* __restrict__ wsA,
                            const unsigned short* __restrict__ wsB2,
                            const int* __restrict__ cnt,
                            const int* __restrict__ csr,
                            float* __restrict__ out) {
    __shared__ float phone[16][257];

    const int tid  = threadIdx.x;
    const int lane = tid & 63;
    const int wv   = tid >> 6;
    const int m16  = lane & 15;
    const int quad = lane >> 4;
    const int rt   = blockIdx.x;
    const int row0 = rt * 16;

    floatx4 acc0 = {0.f,0.f,0.f,0.f}, acc1 = acc0, acc2 = acc0, acc3 = acc0;

    // A: slot (rt*20+s)*64 + lane ; B: slot (s*16 + wv*4+c)*64 + lane   (x8 bf16)
    const unsigned short* aptr = wsA + ((size_t)rt * 20 * 64 + lane) * 8;
    const unsigned short* bptr = wsB2 + ((size_t)(wv * 4) * 64 + lane) * 8;

    #pragma unroll 4
    for (int s = 0; s < NSTEP; ++s) {
        uint4 a  = *(const uint4*)(aptr + (size_t)s * 64 * 8);
        uint4 b0 = *(const uint4*)(bptr + ((size_t)s * 16 + 0) * 64 * 8);
        uint4 b1 = *(const uint4*)(bptr + ((size_t)s * 16 + 1) * 64 * 8);
        uint4 b2 = *(const uint4*)(bptr + ((size_t)s * 16 + 2) * 64 * 8);
        uint4 b3 = *(const uint4*)(bptr + ((size_t)s * 16 + 3) * 64 * 8);
        bf16x8 af = __builtin_bit_cast(bf16x8, a);
        acc0 = __builtin_amdgcn_mfma_f32_16x16x32_bf16(af, __builtin_bit_cast(bf16x8, b0), acc0, 0, 0, 0);
        acc1 = __builtin_amdgcn_mfma_f32_16x16x32_bf16(af, __builtin_bit_cast(bf16x8, b1), acc1, 0, 0, 0);
        acc2 = __builtin_amdgcn_mfma_f32_16x16x32_bf16(af, __builtin_bit_cast(bf16x8, b2), acc2, 0, 0, 0);
        acc3 = __builtin_amdgcn_mfma_f32_16x16x32_bf16(af, __builtin_bit_cast(bf16x8, b3), acc3, 0, 0, 0);
    }

    // C/D layout: col = lane&15, row = quad*4 + reg
    const float scale = 0.03952847075210474f;  // 1/sqrt(640)
    #pragma unroll
    for (int i = 0; i < 4; ++i) {
        int r = quad * 4 + i;
        phone[r][wv * 64 +  0 + m16] = acc0[i] * scale;
        phone[r][wv * 64 + 16 + m16] = acc1[i] * scale;
        phone[r][wv * 64 + 32 + m16] = acc2[i] * scale;
        phone[r][wv * 64 + 48 + m16] = acc3[i] * scale;
    }
    __syncthreads();

    // seg-max + log_softmax: 16 threads per row
    const int r   = tid >> 4;
    const int l16 = tid & 15;
    float pmv[6];
    float mx = -INFINITY;
    #pragma unroll
    for (int j = 0; j < 6; ++j) {
        int m = l16 + j * 16;
        int c = cnt[m];
        const int* lst = csr + m * MAXL;
        float best = -INFINITY;
        for (int jj = 0; jj < c; ++jj) best = fmaxf(best, phone[r][lst[jj]]);
        pmv[j] = best;
        mx = fmaxf(mx, best);
    }
    #pragma unroll
    for (int d = 1; d < 16; d <<= 1) mx = fmaxf(mx, __shfl_xor(mx, d));
    float s = 0.f;
    #pragma unroll
    for (int j = 0; j < 6; ++j) s += __expf(pmv[j] - mx);
    #pragma unroll
    for (int d = 1; d < 16; d <<= 1) s += __shfl_xor(s, d);
    const float lse = mx + __logf(s);
    #pragma unroll
    for (int j = 0; j < 6; ++j)
        out[(size_t)(row0 + r) * NM + l16 + j * 16] = pmv[j] - lse;
}

extern "C" void kernel_launch(void* const* d_in, const int* in_sizes, int n_in,
                              void* d_out, int out_size, void* d_ws, size_t ws_size,
                              hipStream_t stream) {
    const float* enc     = (const float*)d_in[0];   // (8,1024,640) f32
    const float* f2p     = (const float*)d_in[1];   // (640,230) f32
    const float* mapping = (const float*)d_in[2];   // (96,230) f32
    float* out = (float*)d_out;                     // (8,1024,96) f32

    char* ws = (char*)d_ws;
    int* cnt = (int*)(ws + OFF_CNT);
    int* csr = (int*)(ws + OFF_CSR);
    unsigned short* wsB2 = (unsigned short*)(ws + OFF_B);
    unsigned short* wsA  = (unsigned short*)(ws + OFF_A);

    prep_kernel<<<2664, 256, 0, stream>>>(enc, f2p, mapping, cnt, csr, wsB2, wsA);
    fused_phonetics_kernel<<<NRT, 256, 0, stream>>>(wsA, wsB2, cnt, csr, out);
}